// Round 3
// baseline (835.662 us; speedup 1.0000x reference)
//
#include <hip/hip_runtime.h>
#include <hip/hip_bf16.h>
#include <hip/hip_fp16.h>

// SparseGeomAttention: B=8192, K=32, M=16, D=512, H=8, dk=64
// Math restructure: never materialize K_/V_ projections (275 GF saved).
//   Qt[b,h,c] = sum_d Q[b,h,d] W_k[c, h*64+d]         (4.3 GF)
//   scores[b,h,k] = (1/8) sum_c Qt[b,h,c] x_nei[b,k,c] (2.1 GF)
//   attn = softmax(scores + log(tau*pi@ew^T + eps))
//   mixed[b,h,c] = sum_k attn[b,h,k] x_nei[b,k,c]      (2.1 GF)
//   Vh[b,h*64+d] = sum_c mixed[b,h,c] W_v[c,h*64+d]    (4.3 GF)
//   out = Vh @ W_o                                      (4.3 GF)

typedef _Float16 f16;
typedef __attribute__((ext_vector_type(8))) _Float16 f16x8;
typedef __attribute__((ext_vector_type(4))) float f32x4;
typedef unsigned int u32;
typedef unsigned short u16;

#define MFMA16(a, b, c) __builtin_amdgcn_mfma_f32_16x16x32_f16(a, b, c, 0, 0, 0)

__device__ __forceinline__ u32 pk2(float x, float y) {
    f16 a = (f16)x, b = (f16)y;
    u16 ua = __builtin_bit_cast(u16, a), ub = __builtin_bit_cast(u16, b);
    return (u32)ua | ((u32)ub << 16);
}

// ---------------- f32 -> f16 convert (8 elems/thread) ----------------
__global__ void cvt_f16(const float* __restrict__ s, f16* __restrict__ d, int n8) {
    int i = blockIdx.x * blockDim.x + threadIdx.x;
    if (i < n8) {
        float4 a = ((const float4*)s)[i * 2];
        float4 b = ((const float4*)s)[i * 2 + 1];
        f16x8 v;
        v[0] = (f16)a.x; v[1] = (f16)a.y; v[2] = (f16)a.z; v[3] = (f16)a.w;
        v[4] = (f16)b.x; v[5] = (f16)b.y; v[6] = (f16)b.z; v[7] = (f16)b.w;
        ((f16x8*)d)[i] = v;
    }
}

// ------------- transpose W_q/W_v/W_o (512x512) into f16 [j][c] -------------
__global__ void transpose_w_f16(const float* __restrict__ wq, const float* __restrict__ wv,
                                const float* __restrict__ wo, f16* __restrict__ dq,
                                f16* __restrict__ dv, f16* __restrict__ dmo) {
    int z = blockIdx.z;
    const float* s = (z == 0) ? wq : ((z == 1) ? wv : wo);
    f16* d = (z == 0) ? dq : ((z == 1) ? dv : dmo);
    int t = threadIdx.x;
    int j = blockIdx.x * 64 + (t & 63);           // output row (coalesced over lanes)
    int c0 = blockIdx.y * 32 + (t >> 6) * 8;      // 8 source rows
    f16x8 v;
#pragma unroll
    for (int i = 0; i < 8; i++) v[i] = (f16)s[(size_t)(c0 + i) * 512 + j];
    *(f16x8*)&d[(size_t)j * 512 + c0] = v;
}

// ---------------- generic f16 MFMA GEMM: C = A @ Bt^T ----------------
// A: [M x Ktot] row-major (+ per-z column offset), Bt: [N x Ktot] row-major
// tile 128x128, 256 threads, 4 waves (2x2 of 64x64), BK=32, LDS row padded to 40
#define LDSROW 40
template <bool OUTF32>
__global__ __launch_bounds__(256) void gemm16(
    const f16* __restrict__ A, int lda, int aColZ,
    const f16* __restrict__ Bt, int ldb, int btRowZ, int btColZ,
    void* __restrict__ Cv, int ldc, int cColZ,
    int Ktot, int Nvalid) {
    __shared__ __align__(16) f16 aL[128 * LDSROW];
    __shared__ __align__(16) f16 bL[128 * LDSROW];
    int z = blockIdx.z;
    const f16* Ab = A + (size_t)blockIdx.x * 128 * lda + (size_t)z * aColZ;
    const f16* Bb = Bt + ((size_t)blockIdx.y * 128 + (size_t)z * btRowZ) * ldb + (size_t)z * btColZ;
    int t = threadIdx.x, l = t & 63, wid = t >> 6;
    int g = l >> 4, l15 = l & 15;
    int wr = wid >> 1, wc = wid & 1;
    int nclamp = Nvalid - blockIdx.y * 128 - 1;  // clamp Bt staging rows in-bounds
    f32x4 acc[4][4] = {};
    int sr0 = wid * 32 + (l >> 2);
    int sr1 = sr0 + 16;
    int ch = (l & 3) * 8;
    for (int k0 = 0; k0 < Ktot; k0 += 32) {
        __syncthreads();
        f16x8 a0 = *(const f16x8*)(Ab + (size_t)sr0 * lda + k0 + ch);
        f16x8 a1 = *(const f16x8*)(Ab + (size_t)sr1 * lda + k0 + ch);
        int br0 = sr0 <= nclamp ? sr0 : nclamp;
        int br1 = sr1 <= nclamp ? sr1 : nclamp;
        f16x8 b0 = *(const f16x8*)(Bb + (size_t)br0 * ldb + k0 + ch);
        f16x8 b1 = *(const f16x8*)(Bb + (size_t)br1 * ldb + k0 + ch);
        *(f16x8*)&aL[sr0 * LDSROW + ch] = a0;
        *(f16x8*)&aL[sr1 * LDSROW + ch] = a1;
        *(f16x8*)&bL[sr0 * LDSROW + ch] = b0;
        *(f16x8*)&bL[sr1 * LDSROW + ch] = b1;
        __syncthreads();
        f16x8 af[4], bf[4];
#pragma unroll
        for (int m = 0; m < 4; m++) af[m] = *(f16x8*)&aL[(wr * 64 + m * 16 + l15) * LDSROW + g * 8];
#pragma unroll
        for (int n = 0; n < 4; n++) bf[n] = *(f16x8*)&bL[(wc * 64 + n * 16 + l15) * LDSROW + g * 8];
#pragma unroll
        for (int m = 0; m < 4; m++)
#pragma unroll
            for (int n = 0; n < 4; n++)
                acc[m][n] = MFMA16(af[m], bf[n], acc[m][n]);
    }
    size_t row0 = (size_t)blockIdx.x * 128 + wr * 64;
#pragma unroll
    for (int m = 0; m < 4; m++) {
#pragma unroll
        for (int n = 0; n < 4; n++) {
            int cl = blockIdx.y * 128 + wc * 64 + n * 16 + l15;
            if (cl < Nvalid) {
#pragma unroll
                for (int r = 0; r < 4; r++) {
                    size_t off = (row0 + m * 16 + g * 4 + r) * (size_t)ldc + (size_t)z * cColZ + cl;
                    if constexpr (OUTF32) ((float*)Cv)[off] = acc[m][n][r];
                    else ((f16*)Cv)[off] = (f16)acc[m][n][r];
                }
            }
        }
    }
}

// ---------------- fused attention core: one block (1 wave) per b ----------------
// x_nei staged once to LDS f16 in subtiled layout L(k,c) = (c>>4)*512 + (k>>2)*64 + (k&3)*16 + (c&15)
// -> serves scores (contract over c, ds_read_b128) AND mix (contract over k, scalar reads).
// Qt buffer is aliased as the `mixed` output (block b reads only b's Qt before writing b's mixed).
__global__ __launch_bounds__(64) void attn_core(
    const float* __restrict__ xn,   // [B,32,512]
    const float* __restrict__ pi,   // [B,8,16]
    const float* __restrict__ tau,  // [8]
    const float* __restrict__ ew,   // [B,32,16]
    const f16* Qt,                  // [B,4096] (+8KB pad at end)
    f16* mixed)                     // alias of Qt
{
    __shared__ __align__(16) f16 xs[32 * 512];
    __shared__ __align__(16) f16 pis[16 * 32];
    __shared__ __align__(16) f16 ews[32 * 32];
    __shared__ __align__(16) f16 attns[16 * 32];
    __shared__ float taus[8];
    int b = blockIdx.x;
    int l = threadIdx.x, g = l >> 4, l15 = l & 15;

    // zero pad regions of pi/ew tiles (m=16..31 and h=8..15 must be 0)
    u32* pz = (u32*)pis;
    for (int i = l; i < 256; i += 64) pz[i] = 0;
    u32* ez = (u32*)ews;
    for (int i = l; i < 512; i += 64) ez[i] = 0;
    if (l < 8) taus[l] = tau[l];
    __syncthreads();
    // pi -> pis[h][m] f16
    {
        float2 v = ((const float2*)(pi + (size_t)b * 128))[l];
        ((u32*)pis)[(l >> 3) * 16 + (l & 7)] = pk2(v.x, v.y);
    }
    // ew -> ews[k][m] f16
    {
        const float2* e2 = (const float2*)(ew + (size_t)b * 512);
        int k = l >> 1, hh = l & 1;
#pragma unroll
        for (int j = 0; j < 4; j++) {
            float2 v = e2[k * 8 + hh * 4 + j];
            ((u32*)ews)[k * 16 + hh * 4 + j] = pk2(v.x, v.y);
        }
    }
    // x_nei -> subtiled f16 LDS
    {
        const float4* src = (const float4*)(xn + (size_t)b * 16384);
#pragma unroll 8
        for (int i = 0; i < 64; i++) {
            int idx = i * 64 + l;
            float4 v = src[idx];
            int k = idx >> 7, c0 = (idx & 127) << 2;
            uint2 u;
            u.x = pk2(v.x, v.y);
            u.y = pk2(v.z, v.w);
            int e = ((c0 >> 4) << 9) | ((k >> 2) << 6) | ((k & 3) << 4) | (c0 & 15);
            *(uint2*)&xs[e] = u;
        }
    }
    __syncthreads();

    // A_eff = pi @ ew^T via MFMA (padded K=32, zeros beyond m=16)
    f32x4 zz = {};
    f16x8 pa = *(f16x8*)&pis[l15 * 32 + g * 8];
    f16x8 ebf0 = *(f16x8*)&ews[l15 * 32 + g * 8];
    f16x8 ebf1 = *(f16x8*)&ews[(16 + l15) * 32 + g * 8];
    f32x4 ae0 = MFMA16(pa, ebf0, zz);
    f32x4 ae1 = MFMA16(pa, ebf1, zz);
    float bias0[4], bias1[4];
#pragma unroll
    for (int r = 0; r < 4; r++) {
        if (g < 2) {
            float tv = taus[4 * g + r];
            bias0[r] = __logf(tv * ae0[r] + 1e-6f);
            bias1[r] = __logf(tv * ae1[r] + 1e-6f);
        } else {
            bias0[r] = 0.f;
            bias1[r] = 0.f;
        }
    }

    // scores: A = Qt rows h (global loads, h>=8 zeroed), B = x_nei cols k
    f32x4 sc0 = {}, sc1 = {};
    const f16* qb = Qt + (size_t)b * 4096 + (size_t)(l15 < 8 ? l15 : 7) * 512 + g * 8;
#pragma unroll
    for (int kk = 0; kk < 16; kk++) {
        f16x8 a = *(const f16x8*)(qb + kk * 32);
        if (l15 >= 8) {
#pragma unroll
            for (int j = 0; j < 8; j++) a[j] = (f16)0.f;
        }
        int e0 = ((kk * 2 + (g >> 1)) << 9) | ((l15 >> 2) << 6) | ((l15 & 3) << 4) | ((g & 1) << 3);
        f16x8 b0 = *(f16x8*)&xs[e0];
        f16x8 b1 = *(f16x8*)&xs[e0 + 256];
        sc0 = MFMA16(a, b0, sc0);
        sc1 = MFMA16(a, b1, sc1);
    }

    // softmax over k=32 (16 lanes in g-group x 2 in-register values per row)
#pragma unroll
    for (int r = 0; r < 4; r++) {
        float x0 = sc0[r] * 0.125f + bias0[r];
        float x1 = sc1[r] * 0.125f + bias1[r];
        float m = fmaxf(x0, x1);
        m = fmaxf(m, __shfl_xor(m, 1, 64));
        m = fmaxf(m, __shfl_xor(m, 2, 64));
        m = fmaxf(m, __shfl_xor(m, 4, 64));
        m = fmaxf(m, __shfl_xor(m, 8, 64));
        float e0 = __expf(x0 - m), e1 = __expf(x1 - m);
        float s = e0 + e1;
        s += __shfl_xor(s, 1, 64);
        s += __shfl_xor(s, 2, 64);
        s += __shfl_xor(s, 4, 64);
        s += __shfl_xor(s, 8, 64);
        float inv = 1.0f / s;
        float a0 = e0 * inv, a1 = e1 * inv;
        if (g >= 2) { a0 = 0.f; a1 = 0.f; }
        attns[(4 * g + r) * 32 + l15] = (f16)a0;
        attns[(4 * g + r) * 32 + 16 + l15] = (f16)a1;
    }
    __syncthreads();

    // mixed[h,c] = attn @ x_nei  (A = attns rows h, B = x_nei^T via subtiled scalar gathers)
    f16x8 af = *(f16x8*)&attns[l15 * 32 + g * 8];
    size_t ob = (size_t)b * 4096;
#pragma unroll 4
    for (int nt = 0; nt < 32; nt++) {
        f16x8 bf;
        int base = nt * 512 + l15 + g * 128;
#pragma unroll
        for (int s = 0; s < 8; s++) bf[s] = xs[base + (s >> 2) * 64 + (s & 3) * 16];
        f32x4 d = MFMA16(af, bf, zz);
        if (g < 2) {
#pragma unroll
            for (int r = 0; r < 4; r++)
                mixed[ob + (size_t)(4 * g + r) * 512 + nt * 16 + l15] = (f16)d[r];
        }
    }
}

extern "C" void kernel_launch(void* const* d_in, const int* in_sizes, int n_in,
                              void* d_out, int out_size, void* d_ws, size_t ws_size,
                              hipStream_t stream) {
    const float* x_anc = (const float*)d_in[0];
    const float* x_nei = (const float*)d_in[1];
    const float* pi    = (const float*)d_in[2];
    const float* tau   = (const float*)d_in[3];
    const float* ew    = (const float*)d_in[4];
    const float* W_q   = (const float*)d_in[5];
    const float* W_k   = (const float*)d_in[6];
    const float* W_v   = (const float*)d_in[7];
    const float* W_o   = (const float*)d_in[8];
    float* out = (float*)d_out;

    char* w = (char*)d_ws;
    f16* Qt = (f16*)w;          w += 67108864 + 16384;  // [8192,4096] f16 + pad; reused as `mixed`
    f16* xanc16 = (f16*)w;
    f16* Vh = (f16*)w;          w += 8388608;           // xanc16 then reused as Vh
    f16* Q16 = (f16*)w;         w += 8388608;
    f16* wqT = (f16*)w;         w += 524288;
    f16* wk16 = (f16*)w;        w += 524288;
    f16* wvT = (f16*)w;         w += 524288;
    f16* woT = (f16*)w;         w += 524288;

    cvt_f16<<<2048, 256, 0, stream>>>(x_anc, xanc16, 524288);
    cvt_f16<<<128, 256, 0, stream>>>(W_k, wk16, 32768);
    transpose_w_f16<<<dim3(8, 16, 3), 256, 0, stream>>>(W_q, W_v, W_o, wqT, wvT, woT);

    // G1: Q16[b,j] = x_anc @ W_q
    gemm16<false><<<dim3(64, 4, 1), 256, 0, stream>>>(xanc16, 512, 0, wqT, 512, 0, 0,
                                                      Q16, 512, 0, 512, 512);
    // G2 (z=head): Qt[b, h*512+c] = sum_d Q16[b, h*64+d] * W_k[c, h*64+d]
    gemm16<false><<<dim3(64, 4, 8), 256, 0, stream>>>(Q16, 512, 64, wk16, 512, 0, 64,
                                                      Qt, 4096, 512, 64, 512);
    // fused scores/softmax/mix (writes `mixed` into Qt buffer)
    attn_core<<<8192, 64, 0, stream>>>(x_nei, pi, tau, ew, Qt, Qt);

    // G4 (z=head): Vh[b, h*64+n] = sum_c mixed[b, h*512+c] * W_v[c, h*64+n]
    gemm16<false><<<dim3(64, 1, 8), 256, 0, stream>>>(Qt, 4096, 512, wvT, 512, 64, 0,
                                                      Vh, 512, 64, 512, 64);
    // G5: out = Vh @ W_o (f32 output)
    gemm16<true><<<dim3(64, 4, 1), 256, 0, stream>>>(Vh, 512, 0, woT, 512, 0, 0,
                                                     out, 512, 0, 512, 512);
}

// Round 4
// 812.281 us; speedup vs baseline: 1.0288x; 1.0288x over previous
//
#include <hip/hip_runtime.h>
#include <hip/hip_bf16.h>
#include <hip/hip_fp16.h>

// SparseGeomAttention: B=8192, K=32, M=16, D=512, H=8, dk=64
// Math restructure: never materialize K_/V_ projections (275 GF saved).
//   Qt[b,h,c] = sum_d Q[b,h,d] W_k[c, h*64+d]         (4.3 GF)
//   scores[b,h,k] = (1/8) sum_c Qt[b,h,c] x_nei[b,k,c] (2.1 GF)
//   attn = softmax(scores + log(tau*pi@ew^T + eps))
//   mixed[b,h,c] = sum_k attn[b,h,k] x_nei[b,k,c]      (2.1 GF)
//   Vh[b,h*64+d] = sum_c mixed[b,h,c] W_v[c,h*64+d]    (4.3 GF)
//   out = Vh @ W_o                                      (4.3 GF)

typedef _Float16 f16;
typedef __attribute__((ext_vector_type(8))) _Float16 f16x8;
typedef __attribute__((ext_vector_type(4))) float f32x4;
typedef unsigned int u32;
typedef unsigned short u16;

#define MFMA16(a, b, c) __builtin_amdgcn_mfma_f32_16x16x32_f16(a, b, c, 0, 0, 0)

__device__ __forceinline__ u32 pk2(float x, float y) {
    f16 a = (f16)x, b = (f16)y;
    u16 ua = __builtin_bit_cast(u16, a), ub = __builtin_bit_cast(u16, b);
    return (u32)ua | ((u32)ub << 16);
}

// ---------------- f32 -> f16 convert (8 elems/thread) ----------------
__global__ void cvt_f16(const float* __restrict__ s, f16* __restrict__ d, int n8) {
    int i = blockIdx.x * blockDim.x + threadIdx.x;
    if (i < n8) {
        float4 a = ((const float4*)s)[i * 2];
        float4 b = ((const float4*)s)[i * 2 + 1];
        f16x8 v;
        v[0] = (f16)a.x; v[1] = (f16)a.y; v[2] = (f16)a.z; v[3] = (f16)a.w;
        v[4] = (f16)b.x; v[5] = (f16)b.y; v[6] = (f16)b.z; v[7] = (f16)b.w;
        ((f16x8*)d)[i] = v;
    }
}

// ------------- transpose W_q/W_v/W_o (512x512) into f16 [j][c] -------------
__global__ void transpose_w_f16(const float* __restrict__ wq, const float* __restrict__ wv,
                                const float* __restrict__ wo, f16* __restrict__ dq,
                                f16* __restrict__ dv, f16* __restrict__ dmo) {
    int z = blockIdx.z;
    const float* s = (z == 0) ? wq : ((z == 1) ? wv : wo);
    f16* d = (z == 0) ? dq : ((z == 1) ? dv : dmo);
    int t = threadIdx.x;
    int j = blockIdx.x * 64 + (t & 63);           // output row (coalesced over lanes)
    int c0 = blockIdx.y * 32 + (t >> 6) * 8;      // 8 source rows
    f16x8 v;
#pragma unroll
    for (int i = 0; i < 8; i++) v[i] = (f16)s[(size_t)(c0 + i) * 512 + j];
    *(f16x8*)&d[(size_t)j * 512 + c0] = v;
}

// ---------------- generic f16 MFMA GEMM: C = A @ Bt^T ----------------
// A: [M x Ktot] row-major (+ per-z column offset), Bt: [N x Ktot] row-major
// tile 128x128, 256 threads, 4 waves (2x2 of 64x64), BK=32, LDS row padded to 40
#define LDSROW 40
template <bool OUTF32>
__global__ __launch_bounds__(256) void gemm16(
    const f16* __restrict__ A, int lda, int aColZ,
    const f16* __restrict__ Bt, int ldb, int btRowZ, int btColZ,
    void* __restrict__ Cv, int ldc, int cColZ,
    int Ktot, int Nvalid) {
    __shared__ __align__(16) f16 aL[128 * LDSROW];
    __shared__ __align__(16) f16 bL[128 * LDSROW];
    int z = blockIdx.z;
    const f16* Ab = A + (size_t)blockIdx.x * 128 * lda + (size_t)z * aColZ;
    const f16* Bb = Bt + ((size_t)blockIdx.y * 128 + (size_t)z * btRowZ) * ldb + (size_t)z * btColZ;
    int t = threadIdx.x, l = t & 63, wid = t >> 6;
    int g = l >> 4, l15 = l & 15;
    int wr = wid >> 1, wc = wid & 1;
    int nclamp = Nvalid - blockIdx.y * 128 - 1;  // clamp Bt staging rows in-bounds
    f32x4 acc[4][4] = {};
    int sr0 = wid * 32 + (l >> 2);
    int sr1 = sr0 + 16;
    int ch = (l & 3) * 8;
    for (int k0 = 0; k0 < Ktot; k0 += 32) {
        __syncthreads();
        f16x8 a0 = *(const f16x8*)(Ab + (size_t)sr0 * lda + k0 + ch);
        f16x8 a1 = *(const f16x8*)(Ab + (size_t)sr1 * lda + k0 + ch);
        int br0 = sr0 <= nclamp ? sr0 : nclamp;
        int br1 = sr1 <= nclamp ? sr1 : nclamp;
        f16x8 b0 = *(const f16x8*)(Bb + (size_t)br0 * ldb + k0 + ch);
        f16x8 b1 = *(const f16x8*)(Bb + (size_t)br1 * ldb + k0 + ch);
        *(f16x8*)&aL[sr0 * LDSROW + ch] = a0;
        *(f16x8*)&aL[sr1 * LDSROW + ch] = a1;
        *(f16x8*)&bL[sr0 * LDSROW + ch] = b0;
        *(f16x8*)&bL[sr1 * LDSROW + ch] = b1;
        __syncthreads();
        f16x8 af[4], bf[4];
#pragma unroll
        for (int m = 0; m < 4; m++) af[m] = *(f16x8*)&aL[(wr * 64 + m * 16 + l15) * LDSROW + g * 8];
#pragma unroll
        for (int n = 0; n < 4; n++) bf[n] = *(f16x8*)&bL[(wc * 64 + n * 16 + l15) * LDSROW + g * 8];
#pragma unroll
        for (int m = 0; m < 4; m++)
#pragma unroll
            for (int n = 0; n < 4; n++)
                acc[m][n] = MFMA16(af[m], bf[n], acc[m][n]);
    }
    size_t row0 = (size_t)blockIdx.x * 128 + wr * 64;
#pragma unroll
    for (int m = 0; m < 4; m++) {
#pragma unroll
        for (int n = 0; n < 4; n++) {
            int cl = blockIdx.y * 128 + wc * 64 + n * 16 + l15;
            if (cl < Nvalid) {
#pragma unroll
                for (int r = 0; r < 4; r++) {
                    size_t off = (row0 + m * 16 + g * 4 + r) * (size_t)ldc + (size_t)z * cColZ + cl;
                    if constexpr (OUTF32) ((float*)Cv)[off] = acc[m][n][r];
                    else ((f16*)Cv)[off] = (f16)acc[m][n][r];
                }
            }
        }
    }
}

// ---------------- fused attention core: one block (4 waves) per b ----------------
// x_nei staged once to LDS f16 in subtiled layout L(k,c) = (c>>4)*512 + (k>>2)*64 + (k&3)*16 + (c&15)
// -> serves scores (contract over c, ds_read_b128) AND mix (contract over k, scalar reads).
// Wave 0: Qt loads issued early (latency hidden under staging), bias+scores+softmax.
// Waves 1/2: pi/ew staging. All 4 waves: x_nei staging (4-way) and mix (8 nt-tiles each).
// Qt buffer is aliased as the `mixed` output (block b reads only b's Qt before writing b's mixed).
__global__ __launch_bounds__(256) void attn_core(
    const float* __restrict__ xn,   // [B,32,512]
    const float* __restrict__ pi,   // [B,8,16]
    const float* __restrict__ tau,  // [8]
    const float* __restrict__ ew,   // [B,32,16]
    const f16* Qt,                  // [B,4096] (+8KB pad at end)
    f16* mixed)                     // alias of Qt
{
    __shared__ __align__(16) f16 xs[32 * 512];   // 32 KB
    __shared__ __align__(16) f16 pis[16 * 32];   // 1 KB
    __shared__ __align__(16) f16 ews[32 * 32];   // 2 KB
    __shared__ __align__(16) f16 attns[16 * 32]; // 1 KB
    __shared__ float taus[8];
    int b = blockIdx.x;
    int t = threadIdx.x;
    int w = t >> 6, l = t & 63, g = l >> 4, l15 = l & 15;

    // zero pad regions of pi/ew tiles (m=16..31 and h=8..15 must be 0)
    ((u32*)pis)[t] = 0;
    ((u32*)ews)[t] = 0;
    ((u32*)ews)[t + 256] = 0;
    if (t < 8) taus[t] = tau[t];
    __syncthreads();

    // wave 0: issue Qt loads early into registers (latency hides under staging)
    f16x8 qreg[16];
    if (w == 0) {
        const f16* qb = Qt + (size_t)b * 4096 + (size_t)l15 * 512 + g * 8;
#pragma unroll
        for (int kk = 0; kk < 16; kk++) {
            f16x8 qv;
#pragma unroll
            for (int j = 0; j < 8; j++) qv[j] = (f16)0.f;
            if (l15 < 8) qv = *(const f16x8*)(qb + kk * 32);
            qreg[kk] = qv;
        }
    } else if (w == 1) {
        // pi -> pis[h][m] f16
        float2 v = ((const float2*)(pi + (size_t)b * 128))[l];
        ((u32*)pis)[(l >> 3) * 16 + (l & 7)] = pk2(v.x, v.y);
    } else if (w == 2) {
        // ew -> ews[k][m] f16
        const float2* e2 = (const float2*)(ew + (size_t)b * 512);
        int k = l >> 1, hh = l & 1;
#pragma unroll
        for (int j = 0; j < 4; j++) {
            float2 v = e2[k * 8 + hh * 4 + j];
            ((u32*)ews)[k * 16 + hh * 4 + j] = pk2(v.x, v.y);
        }
    }
    // x_nei -> subtiled f16 LDS (all 256 threads, 16 float4 each)
    {
        const float4* src = (const float4*)(xn + (size_t)b * 16384);
#pragma unroll
        for (int i = 0; i < 16; i++) {
            int idx = i * 256 + t;
            float4 v = src[idx];
            int k = idx >> 7, c0 = (idx & 127) << 2;
            uint2 u;
            u.x = pk2(v.x, v.y);
            u.y = pk2(v.z, v.w);
            int e = ((c0 >> 4) << 9) | ((k >> 2) << 6) | ((k & 3) << 4) | (c0 & 15);
            *(uint2*)&xs[e] = u;
        }
    }
    __syncthreads();

    f32x4 zz = {};
    if (w == 0) {
        // A_eff = pi @ ew^T via MFMA (padded K=32, zeros beyond m=16)
        f16x8 pa = *(f16x8*)&pis[l15 * 32 + g * 8];
        f16x8 ebf0 = *(f16x8*)&ews[l15 * 32 + g * 8];
        f16x8 ebf1 = *(f16x8*)&ews[(16 + l15) * 32 + g * 8];
        f32x4 ae0 = MFMA16(pa, ebf0, zz);
        f32x4 ae1 = MFMA16(pa, ebf1, zz);
        float bias0[4], bias1[4];
#pragma unroll
        for (int r = 0; r < 4; r++) {
            if (g < 2) {
                float tv = taus[4 * g + r];
                bias0[r] = __logf(tv * ae0[r] + 1e-6f);
                bias1[r] = __logf(tv * ae1[r] + 1e-6f);
            } else {
                bias0[r] = 0.f;
                bias1[r] = 0.f;
            }
        }

        // scores: A = Qt rows h (registers, h>=8 zeroed), B = x_nei cols k
        f32x4 sc0 = {}, sc1 = {};
#pragma unroll
        for (int kk = 0; kk < 16; kk++) {
            int e0 = ((kk * 2 + (g >> 1)) << 9) | ((l15 >> 2) << 6) | ((l15 & 3) << 4) | ((g & 1) << 3);
            f16x8 b0 = *(f16x8*)&xs[e0];
            f16x8 b1 = *(f16x8*)&xs[e0 + 256];
            sc0 = MFMA16(qreg[kk], b0, sc0);
            sc1 = MFMA16(qreg[kk], b1, sc1);
        }

        // softmax over k=32 (16 lanes in g-group x 2 in-register values per row)
#pragma unroll
        for (int r = 0; r < 4; r++) {
            float x0 = sc0[r] * 0.125f + bias0[r];
            float x1 = sc1[r] * 0.125f + bias1[r];
            float m = fmaxf(x0, x1);
            m = fmaxf(m, __shfl_xor(m, 1, 64));
            m = fmaxf(m, __shfl_xor(m, 2, 64));
            m = fmaxf(m, __shfl_xor(m, 4, 64));
            m = fmaxf(m, __shfl_xor(m, 8, 64));
            float e0 = __expf(x0 - m), e1 = __expf(x1 - m);
            float s = e0 + e1;
            s += __shfl_xor(s, 1, 64);
            s += __shfl_xor(s, 2, 64);
            s += __shfl_xor(s, 4, 64);
            s += __shfl_xor(s, 8, 64);
            float inv = 1.0f / s;
            float a0 = e0 * inv, a1 = e1 * inv;
            if (g >= 2) { a0 = 0.f; a1 = 0.f; }
            attns[(4 * g + r) * 32 + l15] = (f16)a0;
            attns[(4 * g + r) * 32 + 16 + l15] = (f16)a1;
        }
    }
    __syncthreads();

    // mixed[h,c] = attn @ x_nei  (A = attns rows h, B = x_nei^T via subtiled scalar gathers)
    // nt-tiles split across the 4 waves (8 each)
    f16x8 af = *(f16x8*)&attns[l15 * 32 + g * 8];
    size_t ob = (size_t)b * 4096;
#pragma unroll
    for (int j = 0; j < 8; j++) {
        int nt = w * 8 + j;
        f16x8 bf;
        int base = nt * 512 + l15 + g * 128;
#pragma unroll
        for (int s = 0; s < 8; s++) bf[s] = xs[base + (s >> 2) * 64 + (s & 3) * 16];
        f32x4 d = MFMA16(af, bf, zz);
        if (g < 2) {
#pragma unroll
            for (int r = 0; r < 4; r++)
                mixed[ob + (size_t)(4 * g + r) * 512 + nt * 16 + l15] = (f16)d[r];
        }
    }
}

extern "C" void kernel_launch(void* const* d_in, const int* in_sizes, int n_in,
                              void* d_out, int out_size, void* d_ws, size_t ws_size,
                              hipStream_t stream) {
    const float* x_anc = (const float*)d_in[0];
    const float* x_nei = (const float*)d_in[1];
    const float* pi    = (const float*)d_in[2];
    const float* tau   = (const float*)d_in[3];
    const float* ew    = (const float*)d_in[4];
    const float* W_q   = (const float*)d_in[5];
    const float* W_k   = (const float*)d_in[6];
    const float* W_v   = (const float*)d_in[7];
    const float* W_o   = (const float*)d_in[8];
    float* out = (float*)d_out;

    char* w = (char*)d_ws;
    f16* Qt = (f16*)w;          w += 67108864 + 16384;  // [8192,4096] f16 + pad; reused as `mixed`
    f16* xanc16 = (f16*)w;
    f16* Vh = (f16*)w;          w += 8388608;           // xanc16 then reused as Vh
    f16* Q16 = (f16*)w;         w += 8388608;
    f16* wqT = (f16*)w;         w += 524288;
    f16* wk16 = (f16*)w;        w += 524288;
    f16* wvT = (f16*)w;         w += 524288;
    f16* woT = (f16*)w;         w += 524288;

    cvt_f16<<<2048, 256, 0, stream>>>(x_anc, xanc16, 524288);
    cvt_f16<<<128, 256, 0, stream>>>(W_k, wk16, 32768);
    transpose_w_f16<<<dim3(8, 16, 3), 256, 0, stream>>>(W_q, W_v, W_o, wqT, wvT, woT);

    // G1: Q16[b,j] = x_anc @ W_q
    gemm16<false><<<dim3(64, 4, 1), 256, 0, stream>>>(xanc16, 512, 0, wqT, 512, 0, 0,
                                                      Q16, 512, 0, 512, 512);
    // G2 (z=head): Qt[b, h*512+c] = sum_d Q16[b, h*64+d] * W_k[c, h*64+d]
    gemm16<false><<<dim3(64, 4, 8), 256, 0, stream>>>(Q16, 512, 64, wk16, 512, 0, 64,
                                                      Qt, 4096, 512, 64, 512);
    // fused scores/softmax/mix (writes `mixed` into Qt buffer)
    attn_core<<<8192, 256, 0, stream>>>(x_nei, pi, tau, ew, Qt, Qt);

    // G4 (z=head): Vh[b, h*64+n] = sum_c mixed[b, h*512+c] * W_v[c, h*64+n]
    gemm16<false><<<dim3(64, 1, 8), 256, 0, stream>>>(Qt, 4096, 512, wvT, 512, 64, 0,
                                                      Vh, 512, 64, 512, 64);
    // G5: out = Vh @ W_o (f32 output)
    gemm16<true><<<dim3(64, 4, 1), 256, 0, stream>>>(Vh, 512, 0, woT, 512, 0, 0,
                                                     out, 512, 0, 512, 512);
}